// Round 4
// baseline (320.031 us; speedup 1.0000x reference)
//
#include <hip/hip_runtime.h>

// Problem constants
#define BB 8
#define LL 1024
#define KNB 30
#define NUM_RBF 16
#define NPOS 16
#define MAXREL 32
#define EDGE_C 128
#define EDGE_IN 416   // NPOS + 25*NUM_RBF
#define NKK 26        // 416 / 16 K-steps for 32x32x16 MFMA
#define WTF_N (NKK * 4 * 64 * 8)   // 53248 fp16 elements

__constant__ int PAIR_I_d[25] = {0,1,2,3,4,0,0,0,0,1,1,1,4,4,3,1,2,3,4,2,3,4,2,3,2};
__constant__ int PAIR_J_d[25] = {0,1,2,3,4,1,2,3,4,2,3,4,2,3,2,0,0,0,0,1,1,1,4,4,3};

typedef _Float16 half8 __attribute__((ext_vector_type(8)));
typedef float floatx16 __attribute__((ext_vector_type(16)));

// -------- Kernel 0: repack W_edge (416x128 f32) into fragment-linear fp16 --------
// WtF[((kk*4+w)*64+l)*8+j] = W_edge[(kk*16+(l>>5)*8+j)*128 + w*32+(l&31)]
__global__ __launch_bounds__(256) void wprep_kernel(const float* __restrict__ W_edge,
                                                    _Float16* __restrict__ WtF) {
    int o = blockIdx.x * 256 + threadIdx.x;
    if (o >= WTF_N) return;
    int j = o & 7, l = (o >> 3) & 63, w = (o >> 9) & 3, kk = o >> 11;
    int k = (kk << 4) + ((l >> 5) << 3) + j;
    int n = (w << 5) + (l & 31);
    WtF[o] = (_Float16)W_edge[k * EDGE_C + n];
}

// -------- Fused kernel: kNN (4 waves x 1 row) + 4x edge pipeline per block --------
__global__ __launch_bounds__(256) void fused_kernel(const float* __restrict__ X,
                                                    const float* __restrict__ mask,
                                                    const int* __restrict__ ridx,
                                                    const float* __restrict__ W_pos,
                                                    const float* __restrict__ b_pos,
                                                    const _Float16* __restrict__ WtF,
                                                    const float* __restrict__ gamma,
                                                    const float* __restrict__ beta,
                                                    float* __restrict__ out_E,
                                                    float* __restrict__ out_idx) {
    int b = blockIdx.x >> 8;
    int i0 = (blockIdx.x & 255) * 4;
    int tid = threadIdx.x;
    int lane = tid & 63;
    int wv = tid >> 6;

    // LDS overlay:
    //  region A [0, 26624):  phase1 sCa(12288)+sMask(4096); phase2 atoms / fA / Esh
    //  [26624, 29624): dist (750 f32, per-row)
    //  [29624, 30104): nbr4 (4*30 int)
    //  [30104, 30584): dclip4 (4*30 int)
    __shared__ __align__(16) char smem[30584];
    float* sCa = (float*)smem;                    // [3072]
    float* sMask = (float*)(smem + 12288);        // [1024]
    _Float16* fA = (_Float16*)smem;
    float* Esh = (float*)smem;
    float* atoms = (float*)smem;
    float* dist = (float*)(smem + 26624);
    int* nbr4 = (int*)(smem + 29624);
    int* dclip4 = (int*)(smem + 30104);

    // ---------------- Phase 1: kNN, one wave per row ----------------
    for (int j = tid; j < LL; j += 256) {
        int base = (b * LL + j) * 12 + 3;         // Ca
        sCa[j * 3 + 0] = X[base + 0];
        sCa[j * 3 + 1] = X[base + 1];
        sCa[j * 3 + 2] = X[base + 2];
        sMask[j] = mask[b * LL + j];
    }
    __syncthreads();

    {
        int i = i0 + wv;
        int row = b * LL + i;
        float cax = sCa[i * 3 + 0], cay = sCa[i * 3 + 1], caz = sCa[i * 3 + 2];
        float mi = sMask[i];

        float Dv[16];
        float dmax = 0.0f;
#pragma unroll
        for (int c = 0; c < 16; ++c) {
            int j = lane + c * 64;
            float dx = cax - sCa[j * 3 + 0];
            float dy = cay - sCa[j * 3 + 1];
            float dz = caz - sCa[j * 3 + 2];
            float m2 = mi * sMask[j];
            float D = m2 * sqrtf(dx * dx + dy * dy + dz * dz + 1e-6f);
            Dv[c] = D;
            dmax = fmaxf(dmax, D);
        }
        for (int o = 32; o; o >>= 1) dmax = fmaxf(dmax, __shfl_down(dmax, o));
        dmax = __shfl(dmax, 0);

        // exact sortable key: Dadj_bits * 1024 + j  (< 2^41, exact in f64)
        double cand[16];
#pragma unroll
        for (int c = 0; c < 16; ++c) {
            int j = lane + c * 64;
            float m2 = mi * sMask[j];
            float Dadj = Dv[c] + (1.0f - m2) * dmax;
            unsigned int bits = __float_as_uint(Dadj);
            cand[c] = fma((double)bits, 1024.0, (double)j);
        }

        const double KILL = 9.0e15;
        float myj = 0.0f;
        for (int r = 0; r < KNB; ++r) {
            double a0 = fmin(cand[0], cand[1]);
            double a1 = fmin(cand[2], cand[3]);
            double a2 = fmin(cand[4], cand[5]);
            double a3 = fmin(cand[6], cand[7]);
            double a4 = fmin(cand[8], cand[9]);
            double a5 = fmin(cand[10], cand[11]);
            double a6 = fmin(cand[12], cand[13]);
            double a7 = fmin(cand[14], cand[15]);
            a0 = fmin(a0, a1); a2 = fmin(a2, a3); a4 = fmin(a4, a5); a6 = fmin(a6, a7);
            a0 = fmin(a0, a2); a4 = fmin(a4, a6);
            double m = fmin(a0, a4);
            for (int o = 32; o; o >>= 1) {
                double other = __shfl_down(m, o);
                m = fmin(m, other);
            }
            m = __shfl(m, 0);
            unsigned long long ku = (unsigned long long)m;
            int jw = __builtin_amdgcn_readfirstlane((int)(ku & 1023));
            bool own = (lane == (jw & 63));
            switch (jw >> 6) {
                case 0:  if (own) cand[0]  = KILL; break;
                case 1:  if (own) cand[1]  = KILL; break;
                case 2:  if (own) cand[2]  = KILL; break;
                case 3:  if (own) cand[3]  = KILL; break;
                case 4:  if (own) cand[4]  = KILL; break;
                case 5:  if (own) cand[5]  = KILL; break;
                case 6:  if (own) cand[6]  = KILL; break;
                case 7:  if (own) cand[7]  = KILL; break;
                case 8:  if (own) cand[8]  = KILL; break;
                case 9:  if (own) cand[9]  = KILL; break;
                case 10: if (own) cand[10] = KILL; break;
                case 11: if (own) cand[11] = KILL; break;
                case 12: if (own) cand[12] = KILL; break;
                case 13: if (own) cand[13] = KILL; break;
                case 14: if (own) cand[14] = KILL; break;
                case 15: if (own) cand[15] = KILL; break;
            }
            if (lane == r) myj = (float)jw;
        }
        if (lane < KNB) {
            int jn = (int)myj;
            nbr4[wv * KNB + lane] = jn;
            int off = ridx[row] - ridx[b * LL + jn];
            int d = off + MAXREL;
            d = d < 0 ? 0 : (d > 2 * MAXREL ? 2 * MAXREL : d);
            dclip4[wv * KNB + lane] = d;
            out_idx[(size_t)row * KNB + lane] = myj;
        }
    }

    // ---------------- Phase 2: edge pipeline x 4 rows ----------------
    int l = tid & 63;
    const half8* Bp = (const half8*)WtF + wv * 64 + l;   // + kk*256 (invariant)
    int cg = tid & 31;
    int ky = tid >> 5;
    int c0 = cg * 4;
    float gam[4], bet[4];
#pragma unroll
    for (int c = 0; c < 4; ++c) { gam[c] = gamma[c0 + c]; bet[c] = beta[c0 + c]; }

    for (int r = 0; r < 4; ++r) {
        int rowr = b * LL + i0 + r;
        const int* nbr = nbr4 + r * KNB;
        const int* dclip = dclip4 + r * KNB;

        __syncthreads();   // region A free (phase1 / previous row's LN done)

        // atoms for residue i0+r and its 30 neighbors
        if (tid < 31) {
            int rr = (tid == 0) ? (i0 + r) : nbr[tid - 1];
            int base = (b * LL + rr) * 12;
            float Nx = X[base + 0], Ny = X[base + 1], Nz = X[base + 2];
            float Cax = X[base + 3], Cay = X[base + 4], Caz = X[base + 5];
            float Cx = X[base + 6], Cy = X[base + 7], Cz = X[base + 8];
            float Ox = X[base + 9], Oy = X[base + 10], Oz = X[base + 11];
            float bx = Cax - Nx, by = Cay - Ny, bz = Caz - Nz;
            float cx = Cx - Cax, cy = Cy - Cay, cz = Cz - Caz;
            float ax = by * cz - bz * cy;
            float ay = bz * cx - bx * cz;
            float az = bx * cy - by * cx;
            float Cbx = -0.58273431f * ax + 0.56802827f * bx - 0.54067466f * cx + Cax;
            float Cby = -0.58273431f * ay + 0.56802827f * by - 0.54067466f * cy + Cay;
            float Cbz = -0.58273431f * az + 0.56802827f * bz - 0.54067466f * cz + Caz;
            float* A = &atoms[tid * 15];
            A[0] = Cax; A[1] = Cay; A[2] = Caz;
            A[3] = Nx;  A[4] = Ny;  A[5] = Nz;
            A[6] = Cx;  A[7] = Cy;  A[8] = Cz;
            A[9] = Ox;  A[10] = Oy; A[11] = Oz;
            A[12] = Cbx; A[13] = Cby; A[14] = Cbz;
        }
        __syncthreads();

        // 30*25 atom-pair distances
        for (int idx = tid; idx < KNB * 25; idx += 256) {
            int k = idx / 25;
            int p = idx - k * 25;
            const float* Ai = &atoms[PAIR_I_d[p] * 3];
            const float* Aj = &atoms[(1 + k) * 15 + PAIR_J_d[p] * 3];
            float dx = Ai[0] - Aj[0], dy = Ai[1] - Aj[1], dz = Ai[2] - Aj[2];
            dist[idx] = sqrtf(dx * dx + dy * dy + dz * dz + 1e-6f);
        }
        __syncthreads();

        // build A-fragments: element (m,k) -> fA[((k>>4)*64 + m + 32*((k>>3)&1))*8 + (k&7)]
        {
            int m = tid & 31;
            int kgb = tid >> 5;
#pragma unroll
            for (int rr = 0; rr < 7; ++rr) {
                int kg = kgb + 8 * rr;
                if (kg < 52) {
                    half8 v8;
                    if (m >= KNB) {
#pragma unroll
                        for (int jj = 0; jj < 8; ++jj) v8[jj] = (_Float16)0.0f;
                    } else if (kg < 2) {
                        const float* wp = &W_pos[dclip[m] * NPOS + kg * 8];
                        const float* bp = &b_pos[kg * 8];
#pragma unroll
                        for (int jj = 0; jj < 8; ++jj) v8[jj] = (_Float16)(wp[jj] + bp[jj]);
                    } else {
                        int q0 = kg * 8 - 16;
                        int p = q0 >> 4;
                        float t = 0.8f * dist[m * 25 + p] - 1.6f - ((q0 & 8) ? 8.5333336f : 0.0f);
#pragma unroll
                        for (int jj = 0; jj < 8; ++jj) {
                            float x = t - 1.0666667f * (float)jj;
                            v8[jj] = (_Float16)__expf(-x * x);
                        }
                    }
                    int pos = ((kg >> 1) * 64 + m + 32 * (kg & 1)) * 8;
                    *(half8*)(fA + pos) = v8;
                }
            }
        }
        __syncthreads();

        // MFMA K-loop: wave wv -> 32 rows x cols [32wv, 32wv+32)
        floatx16 acc;
#pragma unroll
        for (int q = 0; q < 16; ++q) acc[q] = 0.0f;
        const half8* Ap = (const half8*)fA + l;
#pragma unroll 4
        for (int kk = 0; kk < NKK; ++kk) {
            half8 a = Ap[kk * 64];
            half8 bfr = Bp[kk * 256];
            acc = __builtin_amdgcn_mfma_f32_32x32x16_f16(a, bfr, acc, 0, 0, 0);
        }
        __syncthreads();   // done reading fA before overlay write

        // spill C (layout: col=l&31, row=(q&3)+8*(q>>2)+4*(l>>5))
#pragma unroll
        for (int q = 0; q < 16; ++q) {
            int rr = (q & 3) + 8 * (q >> 2) + 4 * (l >> 5);
            Esh[rr * EDGE_C + wv * 32 + (l & 31)] = acc[q];
        }
        __syncthreads();

        // LayerNorm + store
#pragma unroll
        for (int r2 = 0; r2 < 4; ++r2) {
            int e = ky + 8 * r2;
            float4 v = *(const float4*)&Esh[e * EDGE_C + c0];
            float s = v.x + v.y + v.z + v.w;
            for (int o = 16; o; o >>= 1) s += __shfl_xor(s, o);
            float mean = s * (1.0f / 128.0f);
            float d0 = v.x - mean, d1 = v.y - mean, d2 = v.z - mean, d3 = v.w - mean;
            float vs = d0 * d0 + d1 * d1 + d2 * d2 + d3 * d3;
            for (int o = 16; o; o >>= 1) vs += __shfl_xor(vs, o);
            float inv = 1.0f / sqrtf(vs * (1.0f / 128.0f) + 1e-5f);
            if (e < KNB) {
                float4 o4;
                o4.x = d0 * inv * gam[0] + bet[0];
                o4.y = d1 * inv * gam[1] + bet[1];
                o4.z = d2 * inv * gam[2] + bet[2];
                o4.w = d3 * inv * gam[3] + bet[3];
                *(float4*)(out_E + ((size_t)(rowr * KNB + e)) * EDGE_C + c0) = o4;
            }
        }
    }
}

extern "C" void kernel_launch(void* const* d_in, const int* in_sizes, int n_in,
                              void* d_out, int out_size, void* d_ws, size_t ws_size,
                              hipStream_t stream) {
    const float* X      = (const float*)d_in[0];
    const float* mask   = (const float*)d_in[1];
    const int*   ridx   = (const int*)d_in[2];
    const float* W_pos  = (const float*)d_in[6];
    const float* b_pos  = (const float*)d_in[7];
    const float* W_edge = (const float*)d_in[8];
    const float* gamma  = (const float*)d_in[9];
    const float* beta   = (const float*)d_in[10];

    float* out_E   = (float*)d_out;
    float* out_idx = out_E + (size_t)BB * LL * KNB * EDGE_C;   // E_idx stored as floats
    _Float16* WtF  = (_Float16*)d_ws;                          // 106 KB fragment-linear W

    wprep_kernel<<<(WTF_N + 255) / 256, 256, 0, stream>>>(W_edge, WtF);
    fused_kernel<<<BB * LL / 4, 256, 0, stream>>>(X, mask, ridx, W_pos, b_pos, WtF,
                                                  gamma, beta, out_E, out_idx);
}